// Round 22
// baseline (83.044 us; speedup 1.0000x reference)
//
#include <hip/hip_runtime.h>
#include <hip/hip_bf16.h>
#include <math.h>

#define B_ 4
#define S_ 2048
#define H_ 1024
#define KC 128
#define EPSF 1e-8f

typedef __attribute__((ext_vector_type(8))) short bf16x8;
typedef __attribute__((ext_vector_type(4))) float f32x4;

#define B2F_LO(u) __uint_as_float((u) << 16)
#define B2F_HI(u) __uint_as_float((u) & 0xffff0000u)

static __device__ inline unsigned short f2b(float f) {
    unsigned u = __float_as_uint(f);
    return (unsigned short)((u + 0x7fffu + ((u >> 16) & 1u)) >> 16);  // RNE
}

static __device__ inline void gload16(const void* g, void* l) {
    __builtin_amdgcn_global_load_lds(
        (const __attribute__((address_space(1))) unsigned int*)g,
        (__attribute__((address_space(3))) unsigned int*)l, 16, 0, 0);
}

static __device__ inline unsigned long long shflx64(unsigned long long v, int m) {
    int lo = __shfl_xor((int)(unsigned)(v & 0xffffffffull), m, 64);
    int hi = __shfl_xor((int)(unsigned)(v >> 32), m, 64);
    return ((unsigned long long)(unsigned)hi << 32) | (unsigned)lo;
}

#define CROSS_STAGE(k, j) do {                                              \
    const int lm = (j) >> 3;                                                \
    const bool upL  = (((lane) * 8) & (k)) == 0;                            \
    const bool lowr = ((lane) & lm) == 0;                                   \
    _Pragma("unroll")                                                       \
    for (int r = 0; r < 8; ++r) {                                           \
        unsigned long long o = shflx64(e[r], lm);                           \
        e[r] = ((upL == lowr) == (e[r] < o)) ? e[r] : o;                    \
    }                                                                       \
} while (0)

#define INTRA_STAGE(j, k) do {                                              \
    _Pragma("unroll")                                                       \
    for (int r = 0; r < 8; ++r) if (!(r & (j))) {                           \
        bool up = ((((lane) * 8 + r) & (k)) == 0);                          \
        unsigned long long a = e[r], b = e[r | (j)];                        \
        if (up ? (a > b) : (a < b)) { e[r] = b; e[r | (j)] = a; }           \
    }                                                                       \
} while (0)

static __device__ inline void wave_sort512(unsigned long long e[8], int lane) {
    INTRA_STAGE(1, 2);
    INTRA_STAGE(2, 4);  INTRA_STAGE(1, 4);
    INTRA_STAGE(4, 8);  INTRA_STAGE(2, 8);  INTRA_STAGE(1, 8);
    CROSS_STAGE(16, 8);
    INTRA_STAGE(4, 16); INTRA_STAGE(2, 16); INTRA_STAGE(1, 16);
    CROSS_STAGE(32, 16); CROSS_STAGE(32, 8);
    INTRA_STAGE(4, 32); INTRA_STAGE(2, 32); INTRA_STAGE(1, 32);
    CROSS_STAGE(64, 32); CROSS_STAGE(64, 16); CROSS_STAGE(64, 8);
    INTRA_STAGE(4, 64); INTRA_STAGE(2, 64); INTRA_STAGE(1, 64);
    CROSS_STAGE(128, 64); CROSS_STAGE(128, 32); CROSS_STAGE(128, 16);
    CROSS_STAGE(128, 8);
    INTRA_STAGE(4, 128); INTRA_STAGE(2, 128); INTRA_STAGE(1, 128);
    CROSS_STAGE(256, 128); CROSS_STAGE(256, 64); CROSS_STAGE(256, 32);
    CROSS_STAGE(256, 16); CROSS_STAGE(256, 8);
    INTRA_STAGE(4, 256); INTRA_STAGE(2, 256); INTRA_STAGE(1, 256);
    CROSS_STAGE(512, 256); CROSS_STAGE(512, 128); CROSS_STAGE(512, 64);
    CROSS_STAGE(512, 32); CROSS_STAGE(512, 16); CROSS_STAGE(512, 8);
    INTRA_STAGE(4, 512); INTRA_STAGE(2, 512); INTRA_STAGE(1, 512);
}

static __device__ inline void topk_block(
    const float* logits, const int* mask, int blk,
    int* key_idx, int* val_idx, float* out_idx_base,
    unsigned long long* cand, int tid)
{
    const int b   = blk >> 1;
    const int cls = (blk & 1) ? 2 : 1;
    const int wv = tid >> 6, lane = tid & 63;
    unsigned long long e[8];
    #pragma unroll
    for (int r = 0; r < 8; ++r) {
        int s = wv * 512 + lane * 8 + r;
        float l0 = logits[(b * S_ + s) * 3 + 0];
        float l1 = logits[(b * S_ + s) * 3 + 1];
        float l2 = logits[(b * S_ + s) * 3 + 2];
        int pred = 0; float bl = l0;
        if (l1 > bl) { bl = l1; pred = 1; }
        if (l2 > bl) { bl = l2; pred = 2; }
        float c = -1.0f;
        if (pred == cls && mask[b * S_ + s] == 1) {
            double m = (double)bl;
            double e0 = exp((double)l0 - m);
            double e1 = exp((double)l1 - m);
            double e2 = exp((double)l2 - m);
            c = (float)(((cls == 1) ? e1 : e2) / (e0 + e1 + e2));
        }
        unsigned int u = __float_as_uint(c);
        unsigned int mono = (u & 0x80000000u) ? ~u : (u | 0x80000000u);
        e[r] = ((unsigned long long)(~mono) << 32) | (unsigned int)s;
    }
    wave_sort512(e, lane);
    if (lane < 16) {
        #pragma unroll
        for (int r = 0; r < 8; ++r) cand[wv * 128 + lane * 8 + r] = e[r];
    }
    __syncthreads();
    if (wv == 0) {
        #pragma unroll
        for (int r = 0; r < 8; ++r) e[r] = cand[lane * 8 + r];
        wave_sort512(e, lane);
        if (lane < 16) {
            int* idx_out = (blk & 1) ? (val_idx + b * KC) : (key_idx + b * KC);
            float* oidx  = out_idx_base + ((blk & 1) ? B_ * KC : 0) + b * KC;
            #pragma unroll
            for (int r = 0; r < 8; ++r) {
                int sel = (int)(e[r] & 0xffffffffu);
                idx_out[lane * 8 + r] = sel;
                oidx[lane * 8 + r] = (float)sel;
            }
        }
    }
}

// ------------------------------------------------------------------
// L1: topk (3072..3079) + weight transpose (0..3071) + bf16 MLP-weight
// packing (3080).
// ------------------------------------------------------------------
__global__ __launch_bounds__(256) void prep_kernel(
    const float* __restrict__ Wk, const float* __restrict__ Wv,
    const float* __restrict__ Wbil, unsigned short* __restrict__ Wt,
    const float* __restrict__ logits, const int* __restrict__ mask,
    int* __restrict__ key_idx, int* __restrict__ val_idx,
    const float* __restrict__ Ws1, const float* __restrict__ Ws2,
    const float* __restrict__ Wf1,
    unsigned short* __restrict__ Ws1T_b, unsigned short* __restrict__ Ws2_b,
    unsigned short* __restrict__ Wf1T_b, float* __restrict__ Wf1c0,
    float* __restrict__ out_idx)
{
    __shared__ float tile[32][33];
    __shared__ unsigned long long cand[512];
    const int tid = threadIdx.x;
    if (blockIdx.x < 3072) {
        const int z = blockIdx.x >> 10;
        const int remb = blockIdx.x & 1023;
        const float* Win = (z == 0) ? Wk : (z == 1) ? Wv : Wbil;
        unsigned short* out = Wt + (size_t)z * H_ * H_;
        const int n0 = (remb & 31) * 32, k0 = (remb >> 5) * 32;
        const int r = tid >> 3, c0 = (tid & 7) * 4;
        float4 v = *(const float4*)(Win + (size_t)(k0 + r) * H_ + n0 + c0);
        tile[r][c0 + 0] = v.x; tile[r][c0 + 1] = v.y;
        tile[r][c0 + 2] = v.z; tile[r][c0 + 3] = v.w;
        __syncthreads();
        short4 o;
        o.x = (short)f2b(tile[c0 + 0][r]);
        o.y = (short)f2b(tile[c0 + 1][r]);
        o.z = (short)f2b(tile[c0 + 2][r]);
        o.w = (short)f2b(tile[c0 + 3][r]);
        *(short4*)(out + (size_t)(n0 + r) * H_ + k0 + c0) = o;
        return;
    }
    if (blockIdx.x == 3080) {
        for (int i = tid; i < 512; i += 256) {
            int j = i >> 3, ii = i & 7;
            Ws1T_b[i] = f2b(Ws1[ii * 64 + j]);
        }
        for (int i = tid; i < 2048; i += 256) Ws2_b[i] = f2b(Ws2[i]);
        for (int i = tid; i < 512; i += 256) {
            int t = i >> 5, q = i & 31;
            Wf1T_b[i] = f2b(Wf1[(1 + q) * 16 + t]);
        }
        if (tid < 16) Wf1c0[tid] = Wf1[tid];
        return;
    }
    topk_block(logits, mask, blockIdx.x - 3072, key_idx, val_idx, out_idx,
               cand, tid);
}

// ------------------------------------------------------------------
// L2: gather seq rows by idx, convert to bf16 once.
// ------------------------------------------------------------------
__global__ __launch_bounds__(256) void gatherconv_kernel(
    const float* __restrict__ seq,
    const int* __restrict__ key_idx, const int* __restrict__ val_idx,
    unsigned short* __restrict__ Abf)
{
    const int row = blockIdx.x;
    const int tid = threadIdx.x;
    int b, srow;
    if (row < 512) { b = row >> 7; srow = key_idx[row]; }
    else           { b = (row - 512) >> 7; srow = val_idx[row - 512]; }
    const float* src = seq + ((size_t)b * S_ + srow) * H_ + tid * 4;
    float4 v = *(const float4*)src;
    short4 o;
    o.x = (short)f2b(v.x); o.y = (short)f2b(v.y);
    o.z = (short)f2b(v.z); o.w = (short)f2b(v.w);
    *(short4*)(Abf + (size_t)row * H_ + tid * 4) = o;
}

// ------------------------------------------------------------------
// L3/L4: LDS-staged MFMA GEMM, 64x64 tile, BK=256, 2x2 waves,
// async global_load_lds staging (pre-swizzled source).
// ------------------------------------------------------------------
__global__ __launch_bounds__(256) void gemm_lds_kernel(
    const unsigned short* __restrict__ Ab,
    const unsigned short* __restrict__ Wt,
    const float* __restrict__ b0, const float* __restrict__ b1,
    unsigned short* __restrict__ Cout)
{
    __shared__ __align__(16) char As[64 * 512];
    __shared__ __align__(16) char Bs[64 * 512];

    const int NW8 = gridDim.x >> 3;
    int sw = ((int)blockIdx.x & 7) * NW8 + ((int)blockIdx.x >> 3);
    const int z  = sw >> 7;
    const int r2 = sw & 127;
    const int n0 = (r2 >> 3) * 64;
    const int m0 = (r2 & 7) * 64;

    Ab   += (size_t)z * 512 * H_;
    Cout += (size_t)z * 512 * H_;
    const unsigned short* Wz = Wt + (size_t)z * H_ * H_;
    const float* bias = z ? b1 : b0;

    const int tid  = threadIdx.x;
    const int lane = tid & 63, wv = tid >> 6;
    const int r = lane & 15, g = lane >> 4;
    const int mh = (wv >> 1) * 32, nh = (wv & 1) * 32;

    f32x4 acc[2][2] = {};

    for (int k0 = 0; k0 < H_; k0 += 256) {
        #pragma unroll
        for (int q = 0; q < 8; ++q) {
            const int seg = wv * 8 + q;
            const int row = (seg << 1) | (lane >> 5);
            const int gch = (lane & 31) ^ (row & 7);
            gload16(Ab + (size_t)(m0 + row) * H_ + k0 + gch * 8,
                    As + seg * 1024);
            gload16(Wz + (size_t)(n0 + row) * H_ + k0 + gch * 8,
                    Bs + seg * 1024);
        }
        __syncthreads();
        #pragma unroll
        for (int kk = 0; kk < 8; ++kk) {
            const int c = kk * 4 + g;
            bf16x8 av[2], bv[2];
            #pragma unroll
            for (int i = 0; i < 2; ++i) {
                const int row = mh + i * 16 + r;
                av[i] = *(const bf16x8*)(As + row * 512 + ((c ^ (row & 7)) << 4));
            }
            #pragma unroll
            for (int j = 0; j < 2; ++j) {
                const int row = nh + j * 16 + r;
                bv[j] = *(const bf16x8*)(Bs + row * 512 + ((c ^ (row & 7)) << 4));
            }
            #pragma unroll
            for (int i = 0; i < 2; ++i)
                #pragma unroll
                for (int j = 0; j < 2; ++j)
                    acc[i][j] = __builtin_amdgcn_mfma_f32_16x16x32_bf16(
                        av[i], bv[j], acc[i][j], 0, 0, 0);
        }
        __syncthreads();
    }

    const int orow = (lane >> 4) * 4, ocol = lane & 15;
    #pragma unroll
    for (int i = 0; i < 2; ++i)
        #pragma unroll
        for (int j = 0; j < 2; ++j) {
            const int n = n0 + nh + j * 16 + ocol;
            const float bv_ = bias ? bias[n] : 0.0f;
            #pragma unroll
            for (int gg = 0; gg < 4; ++gg)
                Cout[(size_t)(m0 + mh + i * 16 + orow + gg) * H_ + n]
                    = f2b(acc[i][j][gg] + bv_);
        }
}

// ------------------------------------------------------------------
// L5a: biaffine only (8-wave K-split MFMA); writes f32 c0 into out.
// ------------------------------------------------------------------
__global__ __launch_bounds__(512) void biaffine_kernel(
    const unsigned short* __restrict__ kbt,
    const unsigned short* __restrict__ vrep,
    const float* __restrict__ bbil,
    float* __restrict__ out)
{
    __shared__ float part[8][16][16];
    const int tid = threadIdx.x;
    const int b = blockIdx.x >> 6;
    const int t = blockIdx.x & 63;
    const int m0 = (t >> 3) * 16, n0 = (t & 7) * 16;
    const int lane = tid & 63, wv = tid >> 6;
    const int r = lane & 15, kq = (lane >> 4) * 8;

    f32x4 acc = {};
    const unsigned short* a0 = kbt  + (size_t)(b * KC + m0 + r) * H_ + kq;
    const unsigned short* w0 = vrep + (size_t)(b * KC + n0 + r) * H_ + kq;
    #pragma unroll
    for (int kk = 0; kk < 4; ++kk) {
        int k0 = wv * 128 + kk * 32;
        acc = __builtin_amdgcn_mfma_f32_16x16x32_bf16(
            *(const bf16x8*)(a0 + k0), *(const bf16x8*)(w0 + k0), acc, 0, 0, 0);
    }
    const int orow = (lane >> 4) * 4, ocol = lane & 15;
    #pragma unroll
    for (int g = 0; g < 4; ++g) part[wv][orow + g][ocol] = acc[g];
    __syncthreads();

    if (tid >= 256) return;
    const int kl = tid >> 4, vl = tid & 15;
    float c0 = bbil[0];
    #pragma unroll
    for (int w = 0; w < 8; ++w) c0 += part[w][kl][vl];
    out[((size_t)b * KC + m0 + kl) * KC + n0 + vl] = c0;
}

// ------------------------------------------------------------------
// L5b: spatial MLP. 512 blocks x 128 thr (high occupancy -> latency
// hidden). bf16-packed weights in LDS. Reads c0 from out, overwrites.
// ------------------------------------------------------------------
__global__ __launch_bounds__(128) void mlp_kernel(
    const float* __restrict__ bboxes,
    const int* __restrict__ key_idx, const int* __restrict__ val_idx,
    const unsigned short* __restrict__ Ws1T_b,  // [64][8] bf16
    const float* __restrict__ bs1,
    const unsigned short* __restrict__ Ws2_b,   // [64][32] bf16
    const float* __restrict__ bs2,
    const unsigned short* __restrict__ Wf1T_b,  // [16][32] bf16
    const float* __restrict__ Wf1c0,            // [16] f32
    const float* __restrict__ bf1,
    const float* __restrict__ Wf2, const float* __restrict__ bf2,
    float* __restrict__ out)                    // c0 in, score out
{
    __shared__ uint4 sW1[64];
    __shared__ uint4 sW2[256];
    __shared__ uint4 sWf[64];
    __shared__ float sbs1[64];
    __shared__ float sbs2[32];
    __shared__ float sWf1c0[16];
    __shared__ float sbf1[16];
    __shared__ float sWf2[16];

    const int tid = threadIdx.x;
    if (tid < 64)  sW1[tid] = ((const uint4*)Ws1T_b)[tid];
    for (int i = tid; i < 256; i += 128) sW2[i] = ((const uint4*)Ws2_b)[i];
    if (tid < 64)  sWf[tid] = ((const uint4*)Wf1T_b)[tid];
    if (tid >= 64 && tid < 128) sbs1[tid - 64] = bs1[tid - 64];
    if (tid < 32)  sbs2[tid] = bs2[tid];
    if (tid >= 32 && tid < 48)  sWf1c0[tid - 32] = Wf1c0[tid - 32];
    if (tid >= 48 && tid < 64)  sbf1[tid - 48] = bf1[tid - 48];
    if (tid >= 96 && tid < 112) sWf2[tid - 96] = Wf2[tid - 96];
    __syncthreads();

    const int gid = blockIdx.x * 128 + tid;   // < 65536
    const int b = gid >> 14;
    const int rem = gid & 16383;
    const int k = rem >> 7;
    const int v = rem & 127;

    const float* kbx = bboxes + ((size_t)b * S_ + key_idx[b * KC + k]) * 4;
    const float* vbx = bboxes + ((size_t)b * S_ + val_idx[b * KC + v]) * 4;
    float k0_ = kbx[0], k1_ = kbx[1], k2_ = kbx[2], k3_ = kbx[3];
    float v0_ = vbx[0], v1_ = vbx[1], v2_ = vbx[2], v3_ = vbx[3];

    float kcx = (k0_ + k2_) * 0.5f, kcy = (k1_ + k3_) * 0.5f;
    float vcx = (v0_ + v2_) * 0.5f, vcy = (v1_ + v3_) * 0.5f;
    float dx = vcx - kcx, dy = vcy - kcy;
    float dist = sqrtf(dx * dx + dy * dy + EPSF);
    float angle = atan2f(dy, dx);
    float kh = k3_ - k1_, vh = v3_ - v1_, kw = k2_ - k0_, vw = v2_ - v0_;
    float h_ov = fmaxf(fminf(k3_, v3_) - fmaxf(k1_, v1_), 0.0f);
    float h_align = h_ov / (fminf(kh, vh) + EPSF);
    float v_ov = fmaxf(fminf(k2_, v2_) - fmaxf(k0_, v0_), 0.0f);
    float v_align = v_ov / (fminf(kw, vw) + EPSF);
    float area_ratio = (vh * vw) / (kh * kw + EPSF);
    float aspect = (vw / (vh + EPSF)) / (kw / (kh + EPSF));

    float4 sfa = {dx, dy, dist, angle};
    float4 sfb = {h_align, v_align, area_ratio, aspect};

    float h2[32];
    #pragma unroll
    for (int q = 0; q < 32; ++q) h2[q] = sbs2[q];

    #pragma unroll 4
    for (int j = 0; j < 64; ++j) {
        uint4 w1 = sW1[j];
        float a = sbs1[j]
                + sfa.x * B2F_LO(w1.x) + sfa.y * B2F_HI(w1.x)
                + sfa.z * B2F_LO(w1.y) + sfa.w * B2F_HI(w1.y)
                + sfb.x * B2F_LO(w1.z) + sfb.y * B2F_HI(w1.z)
                + sfb.z * B2F_LO(w1.w) + sfb.w * B2F_HI(w1.w);
        a = fmaxf(a, 0.0f);
        const uint4* w2 = &sW2[j * 4];
        #pragma unroll
        for (int q = 0; q < 4; ++q) {
            uint4 w = w2[q];
            h2[q*8+0] += a * B2F_LO(w.x); h2[q*8+1] += a * B2F_HI(w.x);
            h2[q*8+2] += a * B2F_LO(w.y); h2[q*8+3] += a * B2F_HI(w.y);
            h2[q*8+4] += a * B2F_LO(w.z); h2[q*8+5] += a * B2F_HI(w.z);
            h2[q*8+6] += a * B2F_LO(w.w); h2[q*8+7] += a * B2F_HI(w.w);
        }
    }
    float c0 = out[gid];
    float score = bf2[0];
    #pragma unroll
    for (int tt = 0; tt < 16; ++tt) {
        float f = sbf1[tt] + c0 * sWf1c0[tt];
        const uint4* w = &sWf[tt * 4];
        #pragma unroll
        for (int q = 0; q < 4; ++q) {
            uint4 ww = w[q];
            f += h2[q*8+0] * B2F_LO(ww.x) + h2[q*8+1] * B2F_HI(ww.x)
               + h2[q*8+2] * B2F_LO(ww.y) + h2[q*8+3] * B2F_HI(ww.y)
               + h2[q*8+4] * B2F_LO(ww.z) + h2[q*8+5] * B2F_HI(ww.z)
               + h2[q*8+6] * B2F_LO(ww.w) + h2[q*8+7] * B2F_HI(ww.w);
        }
        score += fmaxf(f, 0.0f) * sWf2[tt];
    }
    out[gid] = score;
}

// ------------------------------------------------------------------
extern "C" void kernel_launch(void* const* d_in, const int* in_sizes, int n_in,
                              void* d_out, int out_size, void* d_ws, size_t ws_size,
                              hipStream_t stream) {
    const float* seq    = (const float*)d_in[0];
    const float* logits = (const float*)d_in[1];
    const float* bboxes = (const float*)d_in[2];
    const int*   mask   = (const int*)d_in[3];
    const float* Wk   = (const float*)d_in[4];
    const float* bk   = (const float*)d_in[5];
    const float* Wv   = (const float*)d_in[6];
    const float* bv   = (const float*)d_in[7];
    const float* Wbil = (const float*)d_in[8];
    const float* bbil = (const float*)d_in[9];
    const float* Ws1  = (const float*)d_in[10];
    const float* bs1  = (const float*)d_in[11];
    const float* Ws2  = (const float*)d_in[12];
    const float* bs2  = (const float*)d_in[13];
    const float* Wf1  = (const float*)d_in[14];
    const float* bf1  = (const float*)d_in[15];
    const float* Wf2  = (const float*)d_in[16];
    const float* bf2  = (const float*)d_in[17];

    float* out = (float*)d_out;
    char* ws = (char*)d_ws;

    int* key_idx = (int*)(ws + 64);
    int* val_idx = key_idx + B_ * KC;
    unsigned short* Wt   = (unsigned short*)(ws + 8192);
    unsigned short* Abf  = Wt + (size_t)3 * H_ * H_;
    unsigned short* reps = Abf + (size_t)1024 * H_;
    unsigned short* kbt  = reps + (size_t)1024 * H_;
    unsigned short* Ws1T_b = kbt + (size_t)512 * H_;
    unsigned short* Ws2_b  = Ws1T_b + 512;
    unsigned short* Wf1T_b = Ws2_b + 2048;
    float* Wf1c0 = (float*)(Wf1T_b + 512);

    prep_kernel<<<3081, 256, 0, stream>>>(Wk, Wv, Wbil, Wt,
                                          logits, mask, key_idx, val_idx,
                                          Ws1, Ws2, Wf1,
                                          Ws1T_b, Ws2_b, Wf1T_b, Wf1c0,
                                          out + B_ * KC * KC);
    gatherconv_kernel<<<1024, 256, 0, stream>>>(seq, key_idx, val_idx, Abf);
    gemm_lds_kernel<<<256, 256, 0, stream>>>(Abf, Wt, bk, bv, reps);
    gemm_lds_kernel<<<128, 256, 0, stream>>>(
        reps, Wt + (size_t)2 * H_ * H_, nullptr, nullptr, kbt);
    biaffine_kernel<<<256, 512, 0, stream>>>(kbt, reps + (size_t)512 * H_,
                                             bbil, out);
    mlp_kernel<<<512, 128, 0, stream>>>(bboxes, key_idx, val_idx,
                                        Ws1T_b, bs1, Ws2_b, bs2,
                                        Wf1T_b, Wf1c0, bf1, Wf2, bf2, out);
}

// Round 23
// 69.928 us; speedup vs baseline: 1.1876x; 1.1876x over previous
//
#include <hip/hip_runtime.h>
#include <hip/hip_bf16.h>
#include <math.h>

#define B_ 4
#define S_ 2048
#define H_ 1024
#define KC 128
#define EPSF 1e-8f

typedef __attribute__((ext_vector_type(8))) short bf16x8;
typedef __attribute__((ext_vector_type(4))) float f32x4;

#define B2F_LO(u) __uint_as_float((u) << 16)
#define B2F_HI(u) __uint_as_float((u) & 0xffff0000u)

static __device__ inline unsigned short f2b(float f) {
    unsigned u = __float_as_uint(f);
    return (unsigned short)((u + 0x7fffu + ((u >> 16) & 1u)) >> 16);  // RNE
}

static __device__ inline void gload16(const void* g, void* l) {
    __builtin_amdgcn_global_load_lds(
        (const __attribute__((address_space(1))) unsigned int*)g,
        (__attribute__((address_space(3))) unsigned int*)l, 16, 0, 0);
}

static __device__ inline unsigned long long shflx64(unsigned long long v, int m) {
    int lo = __shfl_xor((int)(unsigned)(v & 0xffffffffull), m, 64);
    int hi = __shfl_xor((int)(unsigned)(v >> 32), m, 64);
    return ((unsigned long long)(unsigned)hi << 32) | (unsigned)lo;
}

#define CROSS_STAGE(k, j) do {                                              \
    const int lm = (j) >> 3;                                                \
    const bool upL  = (((lane) * 8) & (k)) == 0;                            \
    const bool lowr = ((lane) & lm) == 0;                                   \
    _Pragma("unroll")                                                       \
    for (int r = 0; r < 8; ++r) {                                           \
        unsigned long long o = shflx64(e[r], lm);                           \
        e[r] = ((upL == lowr) == (e[r] < o)) ? e[r] : o;                    \
    }                                                                       \
} while (0)

#define INTRA_STAGE(j, k) do {                                              \
    _Pragma("unroll")                                                       \
    for (int r = 0; r < 8; ++r) if (!(r & (j))) {                           \
        bool up = ((((lane) * 8 + r) & (k)) == 0);                          \
        unsigned long long a = e[r], b = e[r | (j)];                        \
        if (up ? (a > b) : (a < b)) { e[r] = b; e[r | (j)] = a; }           \
    }                                                                       \
} while (0)

static __device__ inline void wave_sort512(unsigned long long e[8], int lane) {
    INTRA_STAGE(1, 2);
    INTRA_STAGE(2, 4);  INTRA_STAGE(1, 4);
    INTRA_STAGE(4, 8);  INTRA_STAGE(2, 8);  INTRA_STAGE(1, 8);
    CROSS_STAGE(16, 8);
    INTRA_STAGE(4, 16); INTRA_STAGE(2, 16); INTRA_STAGE(1, 16);
    CROSS_STAGE(32, 16); CROSS_STAGE(32, 8);
    INTRA_STAGE(4, 32); INTRA_STAGE(2, 32); INTRA_STAGE(1, 32);
    CROSS_STAGE(64, 32); CROSS_STAGE(64, 16); CROSS_STAGE(64, 8);
    INTRA_STAGE(4, 64); INTRA_STAGE(2, 64); INTRA_STAGE(1, 64);
    CROSS_STAGE(128, 64); CROSS_STAGE(128, 32); CROSS_STAGE(128, 16);
    CROSS_STAGE(128, 8);
    INTRA_STAGE(4, 128); INTRA_STAGE(2, 128); INTRA_STAGE(1, 128);
    CROSS_STAGE(256, 128); CROSS_STAGE(256, 64); CROSS_STAGE(256, 32);
    CROSS_STAGE(256, 16); CROSS_STAGE(256, 8);
    INTRA_STAGE(4, 256); INTRA_STAGE(2, 256); INTRA_STAGE(1, 256);
    CROSS_STAGE(512, 256); CROSS_STAGE(512, 128); CROSS_STAGE(512, 64);
    CROSS_STAGE(512, 32); CROSS_STAGE(512, 16); CROSS_STAGE(512, 8);
    INTRA_STAGE(4, 512); INTRA_STAGE(2, 512); INTRA_STAGE(1, 512);
}

static __device__ inline void topk_block(
    const float* logits, const int* mask, int blk,
    int* key_idx, int* val_idx, float* out_idx_base,
    unsigned long long* cand, int tid)
{
    const int b   = blk >> 1;
    const int cls = (blk & 1) ? 2 : 1;
    const int wv = tid >> 6, lane = tid & 63;
    unsigned long long e[8];
    #pragma unroll
    for (int r = 0; r < 8; ++r) {
        int s = wv * 512 + lane * 8 + r;
        float l0 = logits[(b * S_ + s) * 3 + 0];
        float l1 = logits[(b * S_ + s) * 3 + 1];
        float l2 = logits[(b * S_ + s) * 3 + 2];
        int pred = 0; float bl = l0;
        if (l1 > bl) { bl = l1; pred = 1; }
        if (l2 > bl) { bl = l2; pred = 2; }
        float c = -1.0f;
        if (pred == cls && mask[b * S_ + s] == 1) {
            double m = (double)bl;
            double e0 = exp((double)l0 - m);
            double e1 = exp((double)l1 - m);
            double e2 = exp((double)l2 - m);
            c = (float)(((cls == 1) ? e1 : e2) / (e0 + e1 + e2));
        }
        unsigned int u = __float_as_uint(c);
        unsigned int mono = (u & 0x80000000u) ? ~u : (u | 0x80000000u);
        e[r] = ((unsigned long long)(~mono) << 32) | (unsigned int)s;
    }
    wave_sort512(e, lane);
    if (lane < 16) {
        #pragma unroll
        for (int r = 0; r < 8; ++r) cand[wv * 128 + lane * 8 + r] = e[r];
    }
    __syncthreads();
    if (wv == 0) {
        #pragma unroll
        for (int r = 0; r < 8; ++r) e[r] = cand[lane * 8 + r];
        wave_sort512(e, lane);
        if (lane < 16) {
            int* idx_out = (blk & 1) ? (val_idx + b * KC) : (key_idx + b * KC);
            float* oidx  = out_idx_base + ((blk & 1) ? B_ * KC : 0) + b * KC;
            #pragma unroll
            for (int r = 0; r < 8; ++r) {
                int sel = (int)(e[r] & 0xffffffffu);
                idx_out[lane * 8 + r] = sel;
                oidx[lane * 8 + r] = (float)sel;
            }
        }
    }
}

// ------------------------------------------------------------------
// L1: topk (3072..3079) + weight transpose (0..3071) + bf16 MLP-weight
// packing (3080).
// ------------------------------------------------------------------
__global__ __launch_bounds__(256) void prep_kernel(
    const float* __restrict__ Wk, const float* __restrict__ Wv,
    const float* __restrict__ Wbil, unsigned short* __restrict__ Wt,
    const float* __restrict__ logits, const int* __restrict__ mask,
    int* __restrict__ key_idx, int* __restrict__ val_idx,
    const float* __restrict__ Ws1, const float* __restrict__ Ws2,
    const float* __restrict__ Wf1,
    unsigned short* __restrict__ Ws1T_b, unsigned short* __restrict__ Ws2_b,
    unsigned short* __restrict__ Wf1T_b, float* __restrict__ Wf1c0,
    float* __restrict__ out_idx)
{
    __shared__ float tile[32][33];
    __shared__ unsigned long long cand[512];
    const int tid = threadIdx.x;
    if (blockIdx.x < 3072) {
        const int z = blockIdx.x >> 10;
        const int remb = blockIdx.x & 1023;
        const float* Win = (z == 0) ? Wk : (z == 1) ? Wv : Wbil;
        unsigned short* out = Wt + (size_t)z * H_ * H_;
        const int n0 = (remb & 31) * 32, k0 = (remb >> 5) * 32;
        const int r = tid >> 3, c0 = (tid & 7) * 4;
        float4 v = *(const float4*)(Win + (size_t)(k0 + r) * H_ + n0 + c0);
        tile[r][c0 + 0] = v.x; tile[r][c0 + 1] = v.y;
        tile[r][c0 + 2] = v.z; tile[r][c0 + 3] = v.w;
        __syncthreads();
        short4 o;
        o.x = (short)f2b(tile[c0 + 0][r]);
        o.y = (short)f2b(tile[c0 + 1][r]);
        o.z = (short)f2b(tile[c0 + 2][r]);
        o.w = (short)f2b(tile[c0 + 3][r]);
        *(short4*)(out + (size_t)(n0 + r) * H_ + k0 + c0) = o;
        return;
    }
    if (blockIdx.x == 3080) {
        for (int i = tid; i < 512; i += 256) {
            int j = i >> 3, ii = i & 7;
            Ws1T_b[i] = f2b(Ws1[ii * 64 + j]);
        }
        for (int i = tid; i < 2048; i += 256) Ws2_b[i] = f2b(Ws2[i]);
        for (int i = tid; i < 512; i += 256) {
            int t = i >> 5, q = i & 31;
            Wf1T_b[i] = f2b(Wf1[(1 + q) * 16 + t]);
        }
        if (tid < 16) Wf1c0[tid] = Wf1[tid];
        return;
    }
    topk_block(logits, mask, blockIdx.x - 3072, key_idx, val_idx, out_idx,
               cand, tid);
}

// ------------------------------------------------------------------
// L2: gather seq rows by idx, convert to bf16 once.
// ------------------------------------------------------------------
__global__ __launch_bounds__(256) void gatherconv_kernel(
    const float* __restrict__ seq,
    const int* __restrict__ key_idx, const int* __restrict__ val_idx,
    unsigned short* __restrict__ Abf)
{
    const int row = blockIdx.x;
    const int tid = threadIdx.x;
    int b, srow;
    if (row < 512) { b = row >> 7; srow = key_idx[row]; }
    else           { b = (row - 512) >> 7; srow = val_idx[row - 512]; }
    const float* src = seq + ((size_t)b * S_ + srow) * H_ + tid * 4;
    float4 v = *(const float4*)src;
    short4 o;
    o.x = (short)f2b(v.x); o.y = (short)f2b(v.y);
    o.z = (short)f2b(v.z); o.w = (short)f2b(v.w);
    *(short4*)(Abf + (size_t)row * H_ + tid * 4) = o;
}

// ------------------------------------------------------------------
// L3/L4: LDS-staged MFMA GEMM, 64x64 tile, BK=256, 2x2 waves,
// async global_load_lds staging (pre-swizzled source).
// ------------------------------------------------------------------
__global__ __launch_bounds__(256) void gemm_lds_kernel(
    const unsigned short* __restrict__ Ab,
    const unsigned short* __restrict__ Wt,
    const float* __restrict__ b0, const float* __restrict__ b1,
    unsigned short* __restrict__ Cout)
{
    __shared__ __align__(16) char As[64 * 512];
    __shared__ __align__(16) char Bs[64 * 512];

    const int NW8 = gridDim.x >> 3;
    int sw = ((int)blockIdx.x & 7) * NW8 + ((int)blockIdx.x >> 3);
    const int z  = sw >> 7;
    const int r2 = sw & 127;
    const int n0 = (r2 >> 3) * 64;
    const int m0 = (r2 & 7) * 64;

    Ab   += (size_t)z * 512 * H_;
    Cout += (size_t)z * 512 * H_;
    const unsigned short* Wz = Wt + (size_t)z * H_ * H_;
    const float* bias = z ? b1 : b0;

    const int tid  = threadIdx.x;
    const int lane = tid & 63, wv = tid >> 6;
    const int r = lane & 15, g = lane >> 4;
    const int mh = (wv >> 1) * 32, nh = (wv & 1) * 32;

    f32x4 acc[2][2] = {};

    for (int k0 = 0; k0 < H_; k0 += 256) {
        #pragma unroll
        for (int q = 0; q < 8; ++q) {
            const int seg = wv * 8 + q;
            const int row = (seg << 1) | (lane >> 5);
            const int gch = (lane & 31) ^ (row & 7);
            gload16(Ab + (size_t)(m0 + row) * H_ + k0 + gch * 8,
                    As + seg * 1024);
            gload16(Wz + (size_t)(n0 + row) * H_ + k0 + gch * 8,
                    Bs + seg * 1024);
        }
        __syncthreads();
        #pragma unroll
        for (int kk = 0; kk < 8; ++kk) {
            const int c = kk * 4 + g;
            bf16x8 av[2], bv[2];
            #pragma unroll
            for (int i = 0; i < 2; ++i) {
                const int row = mh + i * 16 + r;
                av[i] = *(const bf16x8*)(As + row * 512 + ((c ^ (row & 7)) << 4));
            }
            #pragma unroll
            for (int j = 0; j < 2; ++j) {
                const int row = nh + j * 16 + r;
                bv[j] = *(const bf16x8*)(Bs + row * 512 + ((c ^ (row & 7)) << 4));
            }
            #pragma unroll
            for (int i = 0; i < 2; ++i)
                #pragma unroll
                for (int j = 0; j < 2; ++j)
                    acc[i][j] = __builtin_amdgcn_mfma_f32_16x16x32_bf16(
                        av[i], bv[j], acc[i][j], 0, 0, 0);
        }
        __syncthreads();
    }

    const int orow = (lane >> 4) * 4, ocol = lane & 15;
    #pragma unroll
    for (int i = 0; i < 2; ++i)
        #pragma unroll
        for (int j = 0; j < 2; ++j) {
            const int n = n0 + nh + j * 16 + ocol;
            const float bv_ = bias ? bias[n] : 0.0f;
            #pragma unroll
            for (int gg = 0; gg < 4; ++gg)
                Cout[(size_t)(m0 + mh + i * 16 + orow + gg) * H_ + n]
                    = f2b(acc[i][j][gg] + bv_);
        }
}

// ------------------------------------------------------------------
// L5: biaffine (8-wave K-split MFMA) + spatial MLP with the j-loop
// split across thread pairs (tid, tid+256): waves 4-7 carry half the
// MLP; partials exchanged through padded LDS.
// ------------------------------------------------------------------
__global__ __launch_bounds__(512) void biasp_kernel(
    const unsigned short* __restrict__ kbt,
    const unsigned short* __restrict__ vrep,
    const float* __restrict__ bbil, const float* __restrict__ bboxes,
    const int* __restrict__ key_idx, const int* __restrict__ val_idx,
    const unsigned short* __restrict__ Ws1T_b,  // [64][8] bf16
    const float* __restrict__ bs1,
    const unsigned short* __restrict__ Ws2_b,   // [64][32] bf16
    const float* __restrict__ bs2,
    const unsigned short* __restrict__ Wf1T_b,  // [16][32] bf16
    const float* __restrict__ Wf1c0,            // [16] f32
    const float* __restrict__ bf1,
    const float* __restrict__ Wf2, const float* __restrict__ bf2,
    float* __restrict__ out)
{
    __shared__ float part[8][16][16];
    __shared__ float h2x[256][33];   // bank-conflict-free exchange buffer
    __shared__ uint4 sW1[64];
    __shared__ uint4 sW2[256];
    __shared__ uint4 sWf[64];
    __shared__ float sbs1[64];
    __shared__ float sbs2[32];
    __shared__ float sWf1c0[16];
    __shared__ float sbf1[16];
    __shared__ float sWf2[16];

    const int tid = threadIdx.x;
    if (tid < 64)  sW1[tid] = ((const uint4*)Ws1T_b)[tid];
    if (tid < 256) sW2[tid] = ((const uint4*)Ws2_b)[tid];
    if (tid >= 256 && tid < 320) sWf[tid - 256] = ((const uint4*)Wf1T_b)[tid - 256];
    if (tid >= 320 && tid < 384) sbs1[tid - 320] = bs1[tid - 320];
    if (tid >= 384 && tid < 416) sbs2[tid - 384] = bs2[tid - 384];
    if (tid >= 416 && tid < 432) sWf1c0[tid - 416] = Wf1c0[tid - 416];
    if (tid >= 432 && tid < 448) sbf1[tid - 432] = bf1[tid - 432];
    if (tid >= 448 && tid < 464) sWf2[tid - 448] = Wf2[tid - 448];

    const int b = blockIdx.x >> 6;
    const int t = blockIdx.x & 63;
    const int m0 = (t >> 3) * 16, n0 = (t & 7) * 16;
    const int lane = tid & 63, wv = tid >> 6;    // 8 waves
    const int r = lane & 15, kq = (lane >> 4) * 8;

    f32x4 acc = {};
    const unsigned short* a0 = kbt  + (size_t)(b * KC + m0 + r) * H_ + kq;
    const unsigned short* w0 = vrep + (size_t)(b * KC + n0 + r) * H_ + kq;
    #pragma unroll
    for (int kk = 0; kk < 4; ++kk) {
        int k0 = wv * 128 + kk * 32;
        acc = __builtin_amdgcn_mfma_f32_16x16x32_bf16(
            *(const bf16x8*)(a0 + k0), *(const bf16x8*)(w0 + k0), acc, 0, 0, 0);
    }
    const int orow = (lane >> 4) * 4, ocol = lane & 15;
    #pragma unroll
    for (int g = 0; g < 4; ++g) part[wv][orow + g][ocol] = acc[g];
    __syncthreads();

    // ---- MLP, j-loop split across thread pairs (e, e+256) ----
    const int e = tid & 255;
    const int half = tid >> 8;
    const int kl = e >> 4, vl = e & 15;
    const int kg = m0 + kl, vg = n0 + vl;

    const float* kbx = bboxes + ((size_t)b * S_ + key_idx[b * KC + kg]) * 4;
    const float* vbx = bboxes + ((size_t)b * S_ + val_idx[b * KC + vg]) * 4;
    float k0_ = kbx[0], k1_ = kbx[1], k2_ = kbx[2], k3_ = kbx[3];
    float v0_ = vbx[0], v1_ = vbx[1], v2_ = vbx[2], v3_ = vbx[3];

    float kcx = (k0_ + k2_) * 0.5f, kcy = (k1_ + k3_) * 0.5f;
    float vcx = (v0_ + v2_) * 0.5f, vcy = (v1_ + v3_) * 0.5f;
    float dx = vcx - kcx, dy = vcy - kcy;
    float dist = sqrtf(dx * dx + dy * dy + EPSF);
    float angle = atan2f(dy, dx);
    float kh = k3_ - k1_, vh = v3_ - v1_, kw = k2_ - k0_, vw = v2_ - v0_;
    float h_ov = fmaxf(fminf(k3_, v3_) - fmaxf(k1_, v1_), 0.0f);
    float h_align = h_ov / (fminf(kh, vh) + EPSF);
    float v_ov = fmaxf(fminf(k2_, v2_) - fmaxf(k0_, v0_), 0.0f);
    float v_align = v_ov / (fminf(kw, vw) + EPSF);
    float area_ratio = (vh * vw) / (kh * kw + EPSF);
    float aspect = (vw / (vh + EPSF)) / (kw / (kh + EPSF));

    float4 sfa = {dx, dy, dist, angle};
    float4 sfb = {h_align, v_align, area_ratio, aspect};

    float h2p[32];
    #pragma unroll
    for (int q = 0; q < 32; ++q) h2p[q] = half ? 0.0f : sbs2[q];

    const int jbase = half << 5;
    #pragma unroll 4
    for (int jj = 0; jj < 32; ++jj) {
        const int j = jbase + jj;
        uint4 w1 = sW1[j];
        float a = sbs1[j]
                + sfa.x * B2F_LO(w1.x) + sfa.y * B2F_HI(w1.x)
                + sfa.z * B2F_LO(w1.y) + sfa.w * B2F_HI(w1.y)
                + sfb.x * B2F_LO(w1.z) + sfb.y * B2F_HI(w1.z)
                + sfb.z * B2F_LO(w1.w) + sfb.w * B2F_HI(w1.w);
        a = fmaxf(a, 0.0f);
        const uint4* w2 = &sW2[j * 4];
        #pragma unroll
        for (int q = 0; q < 4; ++q) {
            uint4 w = w2[q];
            h2p[q*8+0] += a * B2F_LO(w.x); h2p[q*8+1] += a * B2F_HI(w.x);
            h2p[q*8+2] += a * B2F_LO(w.y); h2p[q*8+3] += a * B2F_HI(w.y);
            h2p[q*8+4] += a * B2F_LO(w.z); h2p[q*8+5] += a * B2F_HI(w.z);
            h2p[q*8+6] += a * B2F_LO(w.w); h2p[q*8+7] += a * B2F_HI(w.w);
        }
    }
    if (half) {
        #pragma unroll
        for (int q = 0; q < 32; ++q) h2x[e][q] = h2p[q];
    }
    __syncthreads();
    if (half) return;

    float c0 = bbil[0];
    #pragma unroll
    for (int w = 0; w < 8; ++w) c0 += part[w][kl][vl];

    float h2[32];
    #pragma unroll
    for (int q = 0; q < 32; ++q) h2[q] = h2p[q] + h2x[e][q];

    float score = bf2[0];
    #pragma unroll
    for (int tt = 0; tt < 16; ++tt) {
        float f = sbf1[tt] + c0 * sWf1c0[tt];
        const uint4* w = &sWf[tt * 4];
        #pragma unroll
        for (int q = 0; q < 4; ++q) {
            uint4 ww = w[q];
            f += h2[q*8+0] * B2F_LO(ww.x) + h2[q*8+1] * B2F_HI(ww.x)
               + h2[q*8+2] * B2F_LO(ww.y) + h2[q*8+3] * B2F_HI(ww.y)
               + h2[q*8+4] * B2F_LO(ww.z) + h2[q*8+5] * B2F_HI(ww.z)
               + h2[q*8+6] * B2F_LO(ww.w) + h2[q*8+7] * B2F_HI(ww.w);
        }
        score += fmaxf(f, 0.0f) * sWf2[tt];
    }
    out[((size_t)b * KC + kg) * KC + vg] = score;
}

// ------------------------------------------------------------------
extern "C" void kernel_launch(void* const* d_in, const int* in_sizes, int n_in,
                              void* d_out, int out_size, void* d_ws, size_t ws_size,
                              hipStream_t stream) {
    const float* seq    = (const float*)d_in[0];
    const float* logits = (const float*)d_in[1];
    const float* bboxes = (const float*)d_in[2];
    const int*   mask   = (const int*)d_in[3];
    const float* Wk   = (const float*)d_in[4];
    const float* bk   = (const float*)d_in[5];
    const float* Wv   = (const float*)d_in[6];
    const float* bv   = (const float*)d_in[7];
    const float* Wbil = (const float*)d_in[8];
    const float* bbil = (const float*)d_in[9];
    const float* Ws1  = (const float*)d_in[10];
    const float* bs1  = (const float*)d_in[11];
    const float* Ws2  = (const float*)d_in[12];
    const float* bs2  = (const float*)d_in[13];
    const float* Wf1  = (const float*)d_in[14];
    const float* bf1  = (const float*)d_in[15];
    const float* Wf2  = (const float*)d_in[16];
    const float* bf2  = (const float*)d_in[17];

    float* out = (float*)d_out;
    char* ws = (char*)d_ws;

    int* key_idx = (int*)(ws + 64);
    int* val_idx = key_idx + B_ * KC;
    unsigned short* Wt   = (unsigned short*)(ws + 8192);
    unsigned short* Abf  = Wt + (size_t)3 * H_ * H_;
    unsigned short* reps = Abf + (size_t)1024 * H_;
    unsigned short* kbt  = reps + (size_t)1024 * H_;
    unsigned short* Ws1T_b = kbt + (size_t)512 * H_;
    unsigned short* Ws2_b  = Ws1T_b + 512;
    unsigned short* Wf1T_b = Ws2_b + 2048;
    float* Wf1c0 = (float*)(Wf1T_b + 512);

    prep_kernel<<<3081, 256, 0, stream>>>(Wk, Wv, Wbil, Wt,
                                          logits, mask, key_idx, val_idx,
                                          Ws1, Ws2, Wf1,
                                          Ws1T_b, Ws2_b, Wf1T_b, Wf1c0,
                                          out + B_ * KC * KC);
    gatherconv_kernel<<<1024, 256, 0, stream>>>(seq, key_idx, val_idx, Abf);
    gemm_lds_kernel<<<256, 256, 0, stream>>>(Abf, Wt, bk, bv, reps);
    gemm_lds_kernel<<<128, 256, 0, stream>>>(
        reps, Wt + (size_t)2 * H_ * H_, nullptr, nullptr, kbt);
    biasp_kernel<<<256, 512, 0, stream>>>(kbt, reps + (size_t)512 * H_,
                                          bbil, bboxes, key_idx, val_idx,
                                          Ws1T_b, bs1, Ws2_b, bs2,
                                          Wf1T_b, Wf1c0, bf1, Wf2, bf2, out);
}